// Round 19
// baseline (166.994 us; speedup 1.0000x reference)
//
#include <hip/hip_runtime.h>
#include <math.h>

#define B_DIM 8
#define S_DIM 4096
#define D_DIM 1024
#define N_DIM 16
#define ROWS (B_DIM * S_DIM)          // 32768

#define CHUNK_L 32
#define WARM 64
#define STEPS (CHUNK_L + WARM)        // 96
#define NCHAIN (B_DIM * (S_DIM / CHUNK_L))   // 1024 chains

#define KSPLIT 4
#define KQ 256                        // k per block
#define RPB 256                       // rows per block (1 per thread)
#define XB_BLOCKS ((ROWS / RPB) * KSPLIT)   // 128 * 4 = 512 (2 blocks/CU)
#define CW_BLOCKS ((N_DIM * D_DIM) / 256)   // 64

typedef float f32x4 __attribute__((ext_vector_type(4)));
typedef int si16 __attribute__((ext_vector_type(16)));

__device__ __forceinline__ void gl_lds16(const float* g, float* l) {
    __builtin_amdgcn_global_load_lds(
        (const __attribute__((address_space(1))) void*)g,
        (__attribute__((address_space(3))) void*)l, 16, 0, 0);
}

// ---------------------------------------------------------------------------
// k_prep: Bt[n][k] = B[k][n]  (transpose, 64 KB; trivial)
// ---------------------------------------------------------------------------
__global__ __launch_bounds__(256) void k_prep(const float* __restrict__ Bm,
                                              float* __restrict__ Bt) {
    int t = threadIdx.x;                  // 256 threads, 1 block
    int n = t >> 4;                       // 0..15
    int kb = (t & 15) * 64;               // 16 chunks of 64 k
#pragma unroll 8
    for (int j = 0; j < 64; ++j)
        Bt[n * D_DIM + kb + j] = Bm[(size_t)(kb + j) * N_DIM + n];
}

// ---------------------------------------------------------------------------
// Kernel 1 (fused): blocks [0,512): partial xb GEMM.
// Resource model (fits R6..R18): DS pipe is per-CU (12cy/b128, 4 SIMDs
// share) -> need FMA:DS > 24:1; TA processes per-instr line-requests ->
// loads must be lane-contiguous. Design: thread owns 1 row x 16 n.
//  - x: gl_lds staging, 16 full-lines/instr (R12-proven), then ONE
//    ds_read_b128 per 4-k -> FMA:DS = 64:1. XOR-swizzle rule #21.
//  - B: wave-uniform -> inline-asm s_load_dwordx16 into SGPRs (SMEM pipe;
//    FMA src0 = SGPR is free). lgkmcnt(0)+sched_barrier per rule #18.
//  - ksplit 4 -> 512 blocks = 2/CU, 8 waves/CU; 64KB LDS dbuf; m97
//    stage->compute->barrier ordering -> HBM-bound (~21us).
// blocks [512,576): CW[n][d] = sum_k C[n][k]*W[d][k]  (round-1 proven).
// ---------------------------------------------------------------------------
__global__ __launch_bounds__(256) void k_xbcw(const float* __restrict__ x,
                                              const float* __restrict__ Bt,
                                              float* __restrict__ parts,
                                              const float* __restrict__ C,
                                              const float* __restrict__ W,
                                              float* __restrict__ CW) {
    const int t = threadIdx.x;
    if (blockIdx.x >= XB_BLOCKS) {
        int u = (blockIdx.x - XB_BLOCKS) * 256 + t;
        int d = u >> 4;
        int n = u & 15;
        const float* crow = C + n * D_DIM;
        const float* wrow = W + (size_t)d * D_DIM;
        float acc = 0.f;
#pragma unroll 4
        for (int k = 0; k < D_DIM; k += 4) {
            float4 c4 = *(const float4*)(crow + k);
            float4 w4 = *(const float4*)(wrow + k);
            acc = fmaf(c4.x, w4.x, acc);
            acc = fmaf(c4.y, w4.y, acc);
            acc = fmaf(c4.z, w4.z, acc);
            acc = fmaf(c4.w, w4.w, acc);
        }
        CW[n * D_DIM + d] = acc;
        return;
    }
    // ---- xb partial ----
    __shared__ float xs[2][RPB * 32];     // 2 x 32 KB
    const int w = t >> 6;                 // wave 0..3
    const int l = t & 63;
    const int rt = blockIdx.x >> 2;       // row tile 0..127
    const int ks = blockIdx.x & 3;        // k-split 0..3
    const int row0 = rt * RPB;
    const int k0 = ks * KQ;

    // stage chunk CC (32 k) of x: per wave 8 instrs, each 8 rows x 128B
    // contiguous (16 full lines). Source slot pre-swizzled ^(row&7); LDS
    // dest linear (rule #21 both-sides).
#define STAGE(BUF, CC)                                                     \
    {                                                                      \
        const int presw = (l & 7) ^ ((l >> 3) & 7);                        \
        _Pragma("unroll")                                                  \
        for (int j = 0; j < 8; ++j) {                                      \
            int rrel = w * 64 + j * 8 + (l >> 3);                          \
            const float* src = x + (size_t)(row0 + rrel) * D_DIM + k0 +    \
                               (CC) * 32 + presw * 4;                      \
            gl_lds16(src, xs[BUF] + (w * 64 + j * 8) * 32);                \
        }                                                                  \
    }

    STAGE(0, 0)
    __syncthreads();

    const int sw = t & 7;
    float acc[16];
#pragma unroll
    for (int n = 0; n < 16; ++n) acc[n] = 0.f;

    for (int c = 0; c < 8; ++c) {
        if (c < 7) STAGE((c + 1) & 1, c + 1)
        const float* xsb = xs[c & 1] + t * 32;
        // x strip: 8 ds_read_b128 (swizzled slots)
        f32x4 xr0 = *(const f32x4*)(xsb + ((0 ^ sw) * 4));
        f32x4 xr1 = *(const f32x4*)(xsb + ((1 ^ sw) * 4));
        f32x4 xr2 = *(const f32x4*)(xsb + ((2 ^ sw) * 4));
        f32x4 xr3 = *(const f32x4*)(xsb + ((3 ^ sw) * 4));
        f32x4 xr4 = *(const f32x4*)(xsb + ((4 ^ sw) * 4));
        f32x4 xr5 = *(const f32x4*)(xsb + ((5 ^ sw) * 4));
        f32x4 xr6 = *(const f32x4*)(xsb + ((6 ^ sw) * 4));
        f32x4 xr7 = *(const f32x4*)(xsb + ((7 ^ sw) * 4));
#pragma unroll
        for (int np = 0; np < 8; ++np) {
            const int n = np * 2;
            const float* bp0 = Bt + (size_t)n * D_DIM + k0 + c * 32;
            const float* bp1 = bp0 + D_DIM;
            si16 ba, bb, bc, bd;
            asm volatile(
                "s_load_dwordx16 %0, %4, 0x0\n\t"
                "s_load_dwordx16 %1, %4, 0x40\n\t"
                "s_load_dwordx16 %2, %5, 0x0\n\t"
                "s_load_dwordx16 %3, %5, 0x40"
                : "=s"(ba), "=s"(bb), "=s"(bc), "=s"(bd)
                : "s"(bp0), "s"(bp1));
            asm volatile("s_waitcnt lgkmcnt(0)" ::: "memory");
            __builtin_amdgcn_sched_barrier(0);
            union { si16 v; float f[16]; } u0, u1, u2, u3;
            u0.v = ba; u1.v = bb; u2.v = bc; u3.v = bd;
            float a0 = acc[n], a1 = acc[n + 1];
#define FSTEP(XR, S)                                                       \
            a0 = fmaf(XR[0], ((S) < 4 ? u0.f[(S) * 4 + 0]                  \
                                      : u1.f[((S) - 4) * 4 + 0]), a0);     \
            a1 = fmaf(XR[0], ((S) < 4 ? u2.f[(S) * 4 + 0]                  \
                                      : u3.f[((S) - 4) * 4 + 0]), a1);     \
            a0 = fmaf(XR[1], ((S) < 4 ? u0.f[(S) * 4 + 1]                  \
                                      : u1.f[((S) - 4) * 4 + 1]), a0);     \
            a1 = fmaf(XR[1], ((S) < 4 ? u2.f[(S) * 4 + 1]                  \
                                      : u3.f[((S) - 4) * 4 + 1]), a1);     \
            a0 = fmaf(XR[2], ((S) < 4 ? u0.f[(S) * 4 + 2]                  \
                                      : u1.f[((S) - 4) * 4 + 2]), a0);     \
            a1 = fmaf(XR[2], ((S) < 4 ? u2.f[(S) * 4 + 2]                  \
                                      : u3.f[((S) - 4) * 4 + 2]), a1);     \
            a0 = fmaf(XR[3], ((S) < 4 ? u0.f[(S) * 4 + 3]                  \
                                      : u1.f[((S) - 4) * 4 + 3]), a0);     \
            a1 = fmaf(XR[3], ((S) < 4 ? u2.f[(S) * 4 + 3]                  \
                                      : u3.f[((S) - 4) * 4 + 3]), a1);
            FSTEP(xr0, 0) FSTEP(xr1, 1) FSTEP(xr2, 2) FSTEP(xr3, 3)
            FSTEP(xr4, 4) FSTEP(xr5, 5) FSTEP(xr6, 6) FSTEP(xr7, 7)
#undef FSTEP
            acc[n] = a0; acc[n + 1] = a1;
        }
        __syncthreads();
    }
#undef STAGE

    float* op = parts + (size_t)ks * ROWS * N_DIM +
                (size_t)(row0 + t) * N_DIM;
#pragma unroll
    for (int j = 0; j < 4; ++j) {
        f32x4 v = {acc[j * 4 + 0], acc[j * 4 + 1],
                   acc[j * 4 + 2], acc[j * 4 + 3]};
        *(f32x4*)(op + j * 4) = v;
    }
}

// ---------------------------------------------------------------------------
// Kernel 1b: xb = sum of 4 k-split partials (R16-proven)
// ---------------------------------------------------------------------------
__global__ __launch_bounds__(256) void k_red(const float* __restrict__ parts,
                                             float* __restrict__ xb) {
    int i = (blockIdx.x * 256 + threadIdx.x) * 4;
    const size_t Q = (size_t)ROWS * N_DIM;
    float4 a = *(const float4*)(parts + i);
    float4 b = *(const float4*)(parts + Q + i);
    float4 c = *(const float4*)(parts + 2 * Q + i);
    float4 d = *(const float4*)(parts + 3 * Q + i);
    float4 s = {(a.x + b.x) + (c.x + d.x), (a.y + b.y) + (c.y + d.y),
                (a.z + b.z) + (c.z + d.z), (a.w + b.w) + (c.w + d.w)};
    *(float4*)(xb + i) = s;
}

// ---------------------------------------------------------------------------
// Kernel 2: chunked scan (round-6 proven, UNCHANGED)
// ---------------------------------------------------------------------------
__global__ __launch_bounds__(64) void k_scan(const float* __restrict__ xb,
                                             const float* __restrict__ A,
                                             float* __restrict__ hs) {
    const int tid = threadIdx.x;
    const int n = tid & 15;
    const int base4 = (tid & 48) * 4;

    const int chain = blockIdx.x * 4 + (tid >> 4);
    const int b = chain >> 7;
    const int chunk = chain & 127;
    const int t0 = chunk * CHUNK_L - WARM;

    float Ar[16];
#pragma unroll
    for (int m4 = 0; m4 < 16; m4 += 4) {
        float4 v = *(const float4*)(A + n * 16 + m4);
        Ar[m4 + 0] = v.x; Ar[m4 + 1] = v.y; Ar[m4 + 2] = v.z; Ar[m4 + 3] = v.w;
    }

    const float* xp = xb + (size_t)b * S_DIM * N_DIM + n;
    float* hp = hs + (size_t)b * S_DIM * N_DIM + n;

    float ring[8];
#pragma unroll
    for (int i = 0; i < 8; ++i) {
        int tt = t0 + i;
        ring[i] = (tt >= 0) ? xp[(size_t)tt * N_DIM] : 0.f;
    }

    float h = 0.f;
    for (int tr0 = 0; tr0 < STEPS; tr0 += 8) {
#pragma unroll
        for (int j = 0; j < 8; ++j) {
            const int tr = tr0 + j;
            const float xv = ring[j];
            const int hbits = __float_as_int(h);
            int hm[16];
#pragma unroll
            for (int m = 0; m < 16; ++m)
                hm[m] = __builtin_amdgcn_ds_bpermute(base4 + m * 4, hbits);
            float acc0 = xv, acc1 = 0.f;
#pragma unroll
            for (int m = 0; m < 8; ++m) {
                acc0 = fmaf(Ar[m], __int_as_float(hm[m]), acc0);
                acc1 = fmaf(Ar[m + 8], __int_as_float(hm[m + 8]), acc1);
            }
            float g = acc0 + acc1;
            float ax = fabsf(g);
            float e = __expf(2.f * ax);
            float tv = 1.f - 2.f / (e + 1.f);
            h = (g < 0.f) ? -tv : tv;
            if (tr >= WARM)
                hp[(size_t)(t0 + tr) * N_DIM] = h;
            int tt = t0 + tr + 8;
            if (tr + 8 < STEPS)
                ring[j] = (tt >= 0) ? xp[(size_t)tt * N_DIM] : 0.f;
        }
    }
}

// ---------------------------------------------------------------------------
// Kernel 3: out[r][d] = sum_n hs[r][n] * CW[n][d] + bias[d]  (round-1 proven)
// ---------------------------------------------------------------------------
__global__ __launch_bounds__(256) void k_out(const float* __restrict__ hs,
                                             const float* __restrict__ CW,
                                             const float* __restrict__ bias,
                                             float* __restrict__ out) {
    const int t = threadIdx.x;
    const int d0 = t * 4;
    const int row0 = blockIdx.x * 32;
    float4 cw[16];
#pragma unroll
    for (int nn = 0; nn < 16; ++nn)
        cw[nn] = *(const float4*)(CW + nn * D_DIM + d0);
    float4 b4 = *(const float4*)(bias + d0);

    for (int r = row0; r < row0 + 32; ++r) {
        const float4* hp = (const float4*)(hs + (size_t)r * N_DIM);
        float4 h0 = hp[0], h1 = hp[1], h2 = hp[2], h3 = hp[3];
        float hv[16] = {h0.x, h0.y, h0.z, h0.w, h1.x, h1.y, h1.z, h1.w,
                        h2.x, h2.y, h2.z, h2.w, h3.x, h3.y, h3.z, h3.w};
        float4 acc = b4;
#pragma unroll
        for (int nn = 0; nn < 16; ++nn) {
            acc.x = fmaf(hv[nn], cw[nn].x, acc.x);
            acc.y = fmaf(hv[nn], cw[nn].y, acc.y);
            acc.z = fmaf(hv[nn], cw[nn].z, acc.z);
            acc.w = fmaf(hv[nn], cw[nn].w, acc.w);
        }
        *(float4*)(out + (size_t)r * D_DIM + d0) = acc;
    }
}

// ---------------------------------------------------------------------------
extern "C" void kernel_launch(void* const* d_in, const int* in_sizes, int n_in,
                              void* d_out, int out_size, void* d_ws,
                              size_t ws_size, hipStream_t stream) {
    const float* x    = (const float*)d_in[0];   // [8,4096,1024]
    const float* A    = (const float*)d_in[1];   // [16,16]
    const float* Bm   = (const float*)d_in[2];   // [1024,16]
    const float* C    = (const float*)d_in[3];   // [16,1024]
    const float* W    = (const float*)d_in[4];   // [1024,1024]
    const float* bias = (const float*)d_in[5];   // [1024]
    float* out = (float*)d_out;

    float* ws = (float*)d_ws;
    float* xb    = ws;                         // 524288 floats
    float* hs    = ws + 524288;                // 524288
    float* CW    = ws + 1048576;               // 16384
    float* Bt    = ws + 1064960;               // 16384 (64B-aligned)
    float* parts = ws + 1081344;               // 4 * 524288

    k_prep<<<dim3(1), dim3(256), 0, stream>>>(Bm, Bt);
    k_xbcw<<<dim3(XB_BLOCKS + CW_BLOCKS), dim3(256), 0, stream>>>(
        x, Bt, parts, C, W, CW);
    k_red<<<dim3(ROWS * N_DIM / 1024), dim3(256), 0, stream>>>(parts, xb);
    k_scan<<<dim3(NCHAIN / 4), dim3(64), 0, stream>>>(xb, A, hs);
    k_out<<<dim3(ROWS / 32), dim3(256), 0, stream>>>(hs, CW, bias, out);
}